// Round 8
// baseline (752.404 us; speedup 1.0000x reference)
//
#include <hip/hip_runtime.h>
#include <math.h>

// Problem constants (AttentionWriter): B=8,S=1024,M=2048,D=512,H=512,NH=8,Dh=64
#define BB 8
#define SS 1024
#define MM 2048
#define DD 512
#define HH 512
#define NHEAD 8
#define DHEAD 64

typedef __attribute__((ext_vector_type(8))) short short8;
typedef __attribute__((ext_vector_type(4))) float f32x4;
typedef unsigned short us;

// bf16 split helpers (RNE)
__device__ __forceinline__ us bf_hi(float x) {
    unsigned u = __float_as_uint(x);
    return (us)((u + 0x7FFFu + ((u >> 16) & 1u)) >> 16);
}
__device__ __forceinline__ float bf_f(us h) {
    return __uint_as_float(((unsigned)h) << 16);
}
__device__ __forceinline__ void split_pack4(float a, float b, float c, float d,
                                            uint2& hp, uint2& lp) {
    us h0 = bf_hi(a), h1 = bf_hi(b), h2 = bf_hi(c), h3 = bf_hi(d);
    hp.x = (unsigned)h0 | ((unsigned)h1 << 16);
    hp.y = (unsigned)h2 | ((unsigned)h3 << 16);
    us l0 = bf_hi(a - bf_f(h0)), l1 = bf_hi(b - bf_f(h1));
    us l2 = bf_hi(c - bf_f(h2)), l3 = bf_hi(d - bf_f(h3));
    lp.x = (unsigned)l0 | ((unsigned)l1 << 16);
    lp.y = (unsigned)l2 | ((unsigned)l3 << 16);
}

// ---------------------------------------------------------------------------
// f32 GEMM (precision-sensitive importance path ONLY)
// ---------------------------------------------------------------------------
__global__ __launch_bounds__(256) void gemm128(
    const float* __restrict__ A, const float* __restrict__ W,
    const float* __restrict__ bias, float* __restrict__ C,
    int K, int N, int act, const float* __restrict__ rowscale, int rsdiv)
{
    __shared__ float As[8][132];
    __shared__ float Bs[8][128];
    const int tid  = threadIdx.x;
    const int row0 = blockIdx.y * 128, col0 = blockIdx.x * 128;
    const int ty = tid >> 4, tx = tid & 15;

    const int arow = tid >> 1,  ak4  = (tid & 1) * 4;
    const int bk   = tid >> 5,  bcol = (tid & 31) * 4;

    const float* Ap = A + (size_t)(row0 + arow) * K + ak4;
    const float* Wp = W + (size_t)bk * N + col0 + bcol;

    float4 aReg = *(const float4*)Ap;
    float4 bReg = *(const float4*)Wp;

    float acc[8][8];
#pragma unroll
    for (int i = 0; i < 8; ++i)
#pragma unroll
        for (int j = 0; j < 8; ++j) acc[i][j] = 0.f;

    for (int k0 = 0; k0 < K; k0 += 8) {
        __syncthreads();
        As[ak4 + 0][arow] = aReg.x;
        As[ak4 + 1][arow] = aReg.y;
        As[ak4 + 2][arow] = aReg.z;
        As[ak4 + 3][arow] = aReg.w;
        *(float4*)&Bs[bk][bcol] = bReg;
        __syncthreads();
        if (k0 + 8 < K) {
            aReg = *(const float4*)(Ap + k0 + 8);
            bReg = *(const float4*)(Wp + (size_t)(k0 + 8) * N);
        }
#pragma unroll
        for (int kk = 0; kk < 8; ++kk) {
            float a[8], b[8];
            *(float4*)&a[0] = *(const float4*)&As[kk][ty * 8];
            *(float4*)&a[4] = *(const float4*)&As[kk][ty * 8 + 4];
            *(float4*)&b[0] = *(const float4*)&Bs[kk][tx * 4];
            *(float4*)&b[4] = *(const float4*)&Bs[kk][64 + tx * 4];
#pragma unroll
            for (int i = 0; i < 8; ++i)
#pragma unroll
                for (int j = 0; j < 8; ++j)
                    acc[i][j] = fmaf(a[i], b[j], acc[i][j]);
        }
    }

#pragma unroll
    for (int i = 0; i < 8; ++i) {
        const int r = row0 + ty * 8 + i;
        const float sc = rowscale ? rowscale[r / rsdiv] : 1.0f;
#pragma unroll
        for (int half = 0; half < 2; ++half) {
            const int c = col0 + half * 64 + tx * 4;
            float4 bv = bias ? *(const float4*)&bias[c] : make_float4(0.f, 0.f, 0.f, 0.f);
            float4 v;
            v.x = acc[i][half * 4 + 0] + bv.x;
            v.y = acc[i][half * 4 + 1] + bv.y;
            v.z = acc[i][half * 4 + 2] + bv.z;
            v.w = acc[i][half * 4 + 3] + bv.w;
            if (act == 1) {
                v.x = fmaxf(v.x, 0.f); v.y = fmaxf(v.y, 0.f);
                v.z = fmaxf(v.z, 0.f); v.w = fmaxf(v.w, 0.f);
            }
            v.x *= sc; v.y *= sc; v.z *= sc; v.w *= sc;
            *(float4*)&C[(size_t)r * N + c] = v;
        }
    }
}

// ---------------------------------------------------------------------------
// batched transpose+split of [512][512] f32 weights -> [n][k] bf16 hi/lo
// ---------------------------------------------------------------------------
struct TSB {
    const float* src[6];
    us* dh[6];
    us* dl[6];
};
__global__ __launch_bounds__(256) void transpose_split_batch(TSB a)
{
    __shared__ float tile[32][33];
    const int tid = threadIdx.x;
    const int n0 = blockIdx.x * 32, k0 = blockIdx.y * 32;
    const int wsel = blockIdx.z;
    const float* W = a.src[wsel];
    {
        const int r = tid >> 3, c = (tid & 7) * 4;
        const float4 v = *(const float4*)(W + (size_t)(k0 + r) * 512 + n0 + c);
        tile[r][c + 0] = v.x; tile[r][c + 1] = v.y;
        tile[r][c + 2] = v.z; tile[r][c + 3] = v.w;
    }
    __syncthreads();
    {
        const int n = tid >> 3, k = (tid & 7) * 4;
        uint2 hp, lp;
        split_pack4(tile[k + 0][n], tile[k + 1][n], tile[k + 2][n], tile[k + 3][n], hp, lp);
        *(uint2*)(a.dh[wsel] + (size_t)(n0 + n) * 512 + k0 + k) = hp;
        *(uint2*)(a.dl[wsel] + (size_t)(n0 + n) * 512 + k0 + k) = lp;
    }
}

// fused bias for Q: out[n] = b_in @ Wq + bq   (coalesced across n)
__global__ __launch_bounds__(256) void bias_fuse(
    const float* __restrict__ b_in, const float* __restrict__ Wq,
    const float* __restrict__ bq, float* __restrict__ out)
{
    const int n = blockIdx.x * 256 + threadIdx.x;
    float a = bq[n];
    for (int k = 0; k < 512; ++k) a = fmaf(b_in[k], Wq[(size_t)k * 512 + n], a);
    out[n] = a;
}

// concat bk|bv -> bkv[1024]
__global__ __launch_bounds__(256) void concat_bias(
    const float* __restrict__ a, const float* __restrict__ b, float* __restrict__ o)
{
    const int i = blockIdx.x * 256 + threadIdx.x;
    o[i] = (i < 512) ? a[i] : b[i - 512];
}

// ---------------------------------------------------------------------------
// Split-bf16 MFMA GEMM core (3-term), f32 A split in-kernel; B pre-split [N][K].
// Tile 128x128, BK=64, 4 waves (2x2), 4x4 16x16x32 frags/wave. f32 C epilogue.
// ---------------------------------------------------------------------------
#define GEMM_MFMA_BODY(K_)                                                          \
    __shared__ us sm[32768];                                                        \
    us* sAh = sm;            us* sAl = sm + 8192;                                   \
    us* sBh = sm + 16384;    us* sBl = sm + 24576;                                  \
    const int tid = threadIdx.x, lane = tid & 63;                                   \
    const int wid = tid >> 6, wm = wid >> 1, wn = wid & 1;                          \
    const int m0 = blockIdx.y * 128, n0 = blockIdx.x * 128;                         \
    const int fr = lane & 15, fq4 = lane >> 4;                                      \
    f32x4 acc[4][4];                                                                \
    _Pragma("unroll")                                                               \
    for (int i = 0; i < 4; ++i)                                                     \
        _Pragma("unroll")                                                           \
        for (int j = 0; j < 4; ++j)                                                 \
            _Pragma("unroll")                                                       \
            for (int r = 0; r < 4; ++r) acc[i][j][r] = 0.f;                         \
    const int ar = tid >> 4;                                                        \
    const int ak = (tid & 15) * 4;                                                  \
    int bsrow[4], bsf[4], bsoff[4];                                                 \
    _Pragma("unroll")                                                               \
    for (int it = 0; it < 4; ++it) {                                                \
        const int s = tid + 256 * it;                                               \
        bsrow[it] = s >> 3;                                                         \
        bsf[it] = s & 7;                                                            \
        bsoff[it] = bsrow[it] * 64 + ((bsf[it] ^ (bsrow[it] & 7)) << 3);            \
    }                                                                               \
    float4 aR[8];                                                                   \
    uint4 bhR[4], blR[4];                                                           \
    _Pragma("unroll")                                                               \
    for (int p = 0; p < 8; ++p)                                                     \
        aR[p] = *(const float4*)(A + (size_t)(m0 + p * 16 + ar) * (K_) + ak);       \
    _Pragma("unroll")                                                               \
    for (int it = 0; it < 4; ++it) {                                                \
        const size_t bo = (size_t)(n0 + bsrow[it]) * (K_) + bsf[it] * 8;            \
        bhR[it] = *(const uint4*)(Bh + bo);                                         \
        blR[it] = *(const uint4*)(Bl + bo);                                         \
    }                                                                               \
    for (int k0 = 0; k0 < (K_); k0 += 64) {                                         \
        __syncthreads();                                                            \
        _Pragma("unroll")                                                           \
        for (int p = 0; p < 8; ++p) {                                               \
            const int r = p * 16 + ar;                                              \
            const int aoff = r * 128 + (((ak >> 3) ^ (r & 7)) << 4) + ((tid & 1) << 3); \
            uint2 hp, lp;                                                           \
            split_pack4(aR[p].x, aR[p].y, aR[p].z, aR[p].w, hp, lp);                \
            *(uint2*)((char*)sAh + aoff) = hp;                                      \
            *(uint2*)((char*)sAl + aoff) = lp;                                      \
        }                                                                           \
        _Pragma("unroll")                                                           \
        for (int it = 0; it < 4; ++it) {                                            \
            *(uint4*)(sBh + bsoff[it]) = bhR[it];                                   \
            *(uint4*)(sBl + bsoff[it]) = blR[it];                                   \
        }                                                                           \
        __syncthreads();                                                            \
        if (k0 + 64 < (K_)) {                                                       \
            _Pragma("unroll")                                                       \
            for (int p = 0; p < 8; ++p)                                             \
                aR[p] = *(const float4*)(A + (size_t)(m0 + p * 16 + ar) * (K_) + k0 + 64 + ak); \
            _Pragma("unroll")                                                       \
            for (int it = 0; it < 4; ++it) {                                        \
                const size_t bo = (size_t)(n0 + bsrow[it]) * (K_) + k0 + 64 + bsf[it] * 8; \
                bhR[it] = *(const uint4*)(Bh + bo);                                 \
                blR[it] = *(const uint4*)(Bl + bo);                                 \
            }                                                                       \
        }                                                                           \
        _Pragma("unroll")                                                           \
        for (int ks = 0; ks < 2; ++ks) {                                            \
            short8 afh[4], afl[4], bfh[4], bfl[4];                                  \
            _Pragma("unroll")                                                       \
            for (int i = 0; i < 4; ++i) {                                           \
                const int row = wm * 64 + i * 16 + fr;                              \
                const int off = row * 128 + (((ks * 4 + fq4) ^ (row & 7)) << 4);    \
                afh[i] = *(const short8*)((const char*)sAh + off);                  \
                afl[i] = *(const short8*)((const char*)sAl + off);                  \
            }                                                                       \
            _Pragma("unroll")                                                       \
            for (int j = 0; j < 4; ++j) {                                           \
                const int row = wn * 64 + j * 16 + fr;                              \
                const int off = row * 128 + (((ks * 4 + fq4) ^ (row & 7)) << 4);    \
                bfh[j] = *(const short8*)((const char*)sBh + off);                  \
                bfl[j] = *(const short8*)((const char*)sBl + off);                  \
            }                                                                       \
            _Pragma("unroll")                                                       \
            for (int i = 0; i < 4; ++i)                                             \
                _Pragma("unroll")                                                   \
                for (int j = 0; j < 4; ++j) {                                       \
                    acc[i][j] = __builtin_amdgcn_mfma_f32_16x16x32_bf16(afh[i], bfh[j], acc[i][j], 0, 0, 0); \
                    acc[i][j] = __builtin_amdgcn_mfma_f32_16x16x32_bf16(afh[i], bfl[j], acc[i][j], 0, 0, 0); \
                    acc[i][j] = __builtin_amdgcn_mfma_f32_16x16x32_bf16(afl[i], bfh[j], acc[i][j], 0, 0, 0); \
                }                                                                   \
        }                                                                           \
    }

__global__ __launch_bounds__(256) void gemm_mfma(
    const float* __restrict__ A,
    const us* __restrict__ Bh, const us* __restrict__ Bl,
    const float* __restrict__ bias, float* __restrict__ C,
    int K, int N, const float* __restrict__ rowscale, int rsdiv)
{
    GEMM_MFMA_BODY(K)
#pragma unroll
    for (int j = 0; j < 4; ++j) {
        const int col = n0 + wn * 64 + j * 16 + fr;
        const float bj = bias ? bias[col] : 0.f;
#pragma unroll
        for (int i = 0; i < 4; ++i) {
#pragma unroll
            for (int r = 0; r < 4; ++r) {
                const int row = m0 + wm * 64 + i * 16 + fq4 * 4 + r;
                float v = acc[i][j][r] + bj;
                if (rowscale) v *= rowscale[row / rsdiv];
                C[(size_t)row * N + col] = v;
            }
        }
    }
}

// KV GEMM: N=1024 (Wk|Wv). cols<512 -> K rows [B*S][512] bf16 hi/lo;
// cols>=512 -> V TRANSPOSED [B][512 d][1024 s] bf16 hi/lo.
__global__ __launch_bounds__(256) void gemm_mfma_kv(
    const float* __restrict__ A,
    const us* __restrict__ Bh, const us* __restrict__ Bl,
    const float* __restrict__ bias,
    us* __restrict__ Kh, us* __restrict__ Kl,
    us* __restrict__ Vth, us* __restrict__ Vtl, int K)
{
    GEMM_MFMA_BODY(K)
    if (n0 < 512) {
#pragma unroll
        for (int j = 0; j < 4; ++j) {
            const int col = n0 + wn * 64 + j * 16 + fr;
            const float bj = bias[col];
#pragma unroll
            for (int i = 0; i < 4; ++i)
#pragma unroll
                for (int r = 0; r < 4; ++r) {
                    const int row = m0 + wm * 64 + i * 16 + fq4 * 4 + r;
                    const float v = acc[i][j][r] + bj;
                    const us hv = bf_hi(v);
                    Kh[(size_t)row * 512 + col] = hv;
                    Kl[(size_t)row * 512 + col] = bf_hi(v - bf_f(hv));
                }
        }
    } else {
#pragma unroll
        for (int j = 0; j < 4; ++j) {
            const int col = n0 + wn * 64 + j * 16 + fr;
            const float bj = bias[col];
            const int d = col - 512;
#pragma unroll
            for (int i = 0; i < 4; ++i) {
                const int row0 = m0 + wm * 64 + i * 16 + fq4 * 4;
                uint2 hp, lp;
                split_pack4(acc[i][j][0] + bj, acc[i][j][1] + bj,
                            acc[i][j][2] + bj, acc[i][j][3] + bj, hp, lp);
                const size_t vo = ((size_t)(row0 >> 10) * 512 + d) * 1024 + (row0 & 1023);
                *(uint2*)(Vth + vo) = hp;
                *(uint2*)(Vtl + vo) = lp;
            }
        }
    }
}

// ---------------------------------------------------------------------------
// MFMA flash attention v3.2: 64 q-rows/block, LDS 48.25KB -> 3 blocks/CU.
// amdgpu_waves_per_eu(3,3): R6/R7's allocator targeted 8 waves/EU (68 VGPR,
// ~740MB scratch spill traffic/dispatch) while LDS capped occupancy at 3
// blocks/CU anyway. launch_bounds' 2nd arg only sets a MIN waves (reg cap);
// the explicit max=3 here tells codegen to stop trading registers for
// occupancy it cannot realize.
// ---------------------------------------------------------------------------
__global__ __launch_bounds__(256)
__attribute__((amdgpu_waves_per_eu(3, 3)))
void attn_mfma(
    const float* __restrict__ qh,
    const us* __restrict__ Kh, const us* __restrict__ Kl,
    const us* __restrict__ Vth, const us* __restrict__ Vtl,
    float* __restrict__ outp)
{
    __shared__ us sm[24576];    // sKh|sKl|sVh|sVl (4096 us each) | sPh|sPl
    __shared__ float sSc[64];
    us* sKh = sm;            us* sKl = sm + 4096;
    us* sVh = sm + 8192;     us* sVl = sm + 12288;
    us* sPh = sm + 16384;    us* sPl = sm + 20480;

    const int tid = threadIdx.x, lane = tid & 63, w = tid >> 6;
    const int fr = lane & 15, fq4 = lane >> 4;

    // XCD swizzle: 32 blocks sharing one (b,h) K/V slice land on one XCD
    const int wg = blockIdx.x;              // 0..2047
    const int xcd = wg & 7, ix = wg >> 3;   // ix 0..255
    const int mt = ix & 31;
    const int pair = xcd + 8 * (ix >> 5);   // 0..63
    const int h = pair & 7, b = pair >> 3;
    const int m0 = mt * 64;

    const float* Qg = qh + ((size_t)(b * MM + m0)) * HH + h * DHEAD;
    const us* Kgh = Kh + ((size_t)b * SS) * 512 + h * DHEAD;
    const us* Kgl = Kl + ((size_t)b * SS) * 512 + h * DHEAD;
    const us* Vgh = Vth + ((size_t)b * 512 + h * DHEAD) * 1024;
    const us* Vgl = Vtl + ((size_t)b * 512 + h * DHEAD) * 1024;
    float* Og = outp + ((size_t)(b * MM + m0)) * HH + h * DHEAD;

    // ---- Q fragments in registers (pre-scaled by 1/8), hi/lo split
    short8 qfh[2], qfl[2];   // [ks]
#pragma unroll
    for (int ks = 0; ks < 2; ++ks) {
        const float* qp = Qg + (size_t)(w * 16 + fr) * HH + ks * 32 + fq4 * 8;
        const float4 u0 = *(const float4*)qp;
        const float4 u1 = *(const float4*)(qp + 4);
        float v[8] = {u0.x, u0.y, u0.z, u0.w, u1.x, u1.y, u1.z, u1.w};
#pragma unroll
        for (int e = 0; e < 8; ++e) {
            const float x = v[e] * 0.125f;
            const us hb = bf_hi(x);
            qfh[ks][e] = (short)hb;
            qfl[ks][e] = (short)bf_hi(x - bf_f(hb));
        }
    }

    // uint4 staging: thread covers (row = p*32 + tid>>3, frag = tid&7)
    const int srow = tid >> 3;     // 0..31
    const int sfl  = tid & 7;      // frag index 0..7

    uint4 kh4[2], kl4[2], vh4[2], vl4[2];
#define LOADKV(t)                                                                   \
    {                                                                               \
        _Pragma("unroll")                                                           \
        for (int p = 0; p < 2; ++p) {                                               \
            const int row = p * 32 + srow;                                          \
            const size_t ko = (size_t)((t) * 64 + row) * 512 + sfl * 8;             \
            kh4[p] = *(const uint4*)(Kgh + ko);                                     \
            kl4[p] = *(const uint4*)(Kgl + ko);                                     \
            const size_t vo = (size_t)row * 1024 + (t) * 64 + sfl * 8;              \
            vh4[p] = *(const uint4*)(Vgh + vo);                                     \
            vl4[p] = *(const uint4*)(Vgl + vo);                                     \
        }                                                                           \
    }
#define STOREKV()                                                                   \
    {                                                                               \
        _Pragma("unroll")                                                           \
        for (int p = 0; p < 2; ++p) {                                               \
            const int row = p * 32 + srow;                                          \
            const int off = row * 128 + ((sfl ^ (row & 7)) << 4);                   \
            *(uint4*)((char*)sKh + off) = kh4[p];                                   \
            *(uint4*)((char*)sKl + off) = kl4[p];                                   \
            *(uint4*)((char*)sVh + off) = vh4[p];                                   \
            *(uint4*)((char*)sVl + off) = vl4[p];                                   \
        }                                                                           \
    }

    f32x4 oacc[4];
#pragma unroll
    for (int j = 0; j < 4; ++j)
#pragma unroll
        for (int r = 0; r < 4; ++r) oacc[j][r] = 0.f;
    float mrun = -1e30f, lrun = 0.f;

    LOADKV(0);
    for (int t = 0; t < SS / 64; ++t) {
        __syncthreads();                 // prev chunk's K/V reads done
        STOREKV();
        __syncthreads();                 // staging visible
        if (t < SS / 64 - 1) LOADKV(t + 1);

        // ---- QK^T (swapped): stt[fs] = K-slice x Q^T; C: row=s, col=q=fr
        f32x4 stt[4];
#pragma unroll
        for (int fs = 0; fs < 4; ++fs)
#pragma unroll
            for (int r = 0; r < 4; ++r) stt[fs][r] = 0.f;
#pragma unroll
        for (int ks = 0; ks < 2; ++ks) {
            short8 kfh[4], kfl[4];
#pragma unroll
            for (int fs = 0; fs < 4; ++fs) {
                const int row = fs * 16 + fr;
                const int off = row * 128 + (((ks * 4 + fq4) ^ (row & 7)) << 4);
                kfh[fs] = *(const short8*)((const char*)sKh + off);
                kfl[fs] = *(const short8*)((const char*)sKl + off);
            }
#pragma unroll
            for (int fs = 0; fs < 4; ++fs) {
                stt[fs] = __builtin_amdgcn_mfma_f32_16x16x32_bf16(kfh[fs], qfh[ks], stt[fs], 0, 0, 0);
                stt[fs] = __builtin_amdgcn_mfma_f32_16x16x32_bf16(kfh[fs], qfl[ks], stt[fs], 0, 0, 0);
                stt[fs] = __builtin_amdgcn_mfma_f32_16x16x32_bf16(kfl[fs], qfh[ks], stt[fs], 0, 0, 0);
            }
        }

        // ---- online softmax (q = fr; s spans 4 regs x 4 fs x 4 quarters)
        {
            float mx = stt[0][0];
#pragma unroll
            for (int fs = 0; fs < 4; ++fs)
#pragma unroll
                for (int r = 0; r < 4; ++r) mx = fmaxf(mx, stt[fs][r]);
            mx = fmaxf(mx, __shfl_xor(mx, 16));
            mx = fmaxf(mx, __shfl_xor(mx, 32));
            const float nm = fmaxf(mrun, mx);
            const float scf = __expf(mrun - nm);
            mrun = nm;
            float ps = 0.f;
#pragma unroll
            for (int fs = 0; fs < 4; ++fs)
#pragma unroll
                for (int r = 0; r < 4; ++r) {
                    const float p = __expf(stt[fs][r] - nm);
                    stt[fs][r] = p;
                    ps += p;
                }
            ps += __shfl_xor(ps, 16);
            ps += __shfl_xor(ps, 32);
            lrun = lrun * scf + ps;
            if (fq4 == 0) sSc[w * 16 + fr] = scf;
        }

        // ---- write P[q][s] hi/lo (wave-private rows, no barrier needed)
#pragma unroll
        for (int fs = 0; fs < 4; ++fs) {
            const int q = w * 16 + fr;
            const int flog = (fs << 1) | (fq4 >> 1);
            const int off = q * 128 + ((flog ^ (q & 7)) << 4) + ((fq4 & 1) << 3);
            uint2 hp, lp;
            split_pack4(stt[fs][0], stt[fs][1], stt[fs][2], stt[fs][3], hp, lp);
            *(uint2*)((char*)sPh + off) = hp;
            *(uint2*)((char*)sPl + off) = lp;
        }

        // ---- rescale oacc (q = w*16 + fq4*4 + r)
#pragma unroll
        for (int r = 0; r < 4; ++r) {
            const float scv = sSc[w * 16 + fq4 * 4 + r];
#pragma unroll
            for (int fd = 0; fd < 4; ++fd) oacc[fd][r] *= scv;
        }

        // ---- PV: oacc[fd] += P x V
#pragma unroll
        for (int ks = 0; ks < 2; ++ks) {
            short8 pfh, pfl, vfh[4], vfl[4];
            {
                const int row = w * 16 + fr;
                const int off = row * 128 + (((ks * 4 + fq4) ^ (row & 7)) << 4);
                pfh = *(const short8*)((const char*)sPh + off);
                pfl = *(const short8*)((const char*)sPl + off);
            }
#pragma unroll
            for (int fd = 0; fd < 4; ++fd) {
                const int row = fd * 16 + fr;
                const int off = row * 128 + (((ks * 4 + fq4) ^ (row & 7)) << 4);
                vfh[fd] = *(const short8*)((const char*)sVh + off);
                vfl[fd] = *(const short8*)((const char*)sVl + off);
            }
#pragma unroll
            for (int fd = 0; fd < 4; ++fd) {
                oacc[fd] = __builtin_amdgcn_mfma_f32_16x16x32_bf16(pfh, vfh[fd], oacc[fd], 0, 0, 0);
                oacc[fd] = __builtin_amdgcn_mfma_f32_16x16x32_bf16(pfh, vfl[fd], oacc[fd], 0, 0, 0);
                oacc[fd] = __builtin_amdgcn_mfma_f32_16x16x32_bf16(pfl, vfh[fd], oacc[fd], 0, 0, 0);
            }
        }
    }

    // ---- normalize + store
    if (fq4 == 0) sSc[w * 16 + fr] = lrun;
#pragma unroll
    for (int r = 0; r < 4; ++r) {
        const float inv = 1.0f / sSc[w * 16 + fq4 * 4 + r];
        const int q = w * 16 + fq4 * 4 + r;
#pragma unroll
        for (int fd = 0; fd < 4; ++fd)
            Og[(size_t)q * HH + fd * 16 + fr] = oacc[fd][r] * inv;
    }
}

// imp[row] = sigmoid(dot(h1[row,0:256], Wi2) + bi2); one wave per row
__global__ __launch_bounds__(256) void imp_kernel(
    const float* __restrict__ h1, const float* __restrict__ Wi2,
    const float* __restrict__ bi2, float* __restrict__ imp)
{
    const int wv = threadIdx.x >> 6, lane = threadIdx.x & 63;
    const int row = blockIdx.x * 4 + wv;
    const float4 hv = *(const float4*)(h1 + (size_t)row * 256 + lane * 4);
    const float4 wvv = *(const float4*)(Wi2 + lane * 4);
    float s = hv.x * wvv.x + hv.y * wvv.y + hv.z * wvv.z + hv.w * wvv.w;
#pragma unroll
    for (int m = 1; m < 64; m <<= 1) s += __shfl_xor(s, m);
    if (lane == 0) imp[row] = 1.0f / (1.0f + expf(-(s + bi2[0])));
}

// per batch: mean(imp), last index with imp>0.5, exists
__global__ __launch_bounds__(256) void impstats_kernel(
    const float* __restrict__ imp, float* __restrict__ imp_mean,
    int* __restrict__ s_star, int* __restrict__ exists)
{
    const int b = blockIdx.x, tid = threadIdx.x;
    float sum = 0.f; int last = -1;
    for (int s = tid; s < SS; s += 256) {
        const float v = imp[b * SS + s];
        sum += v;
        if (v > 0.5f) last = s;
    }
#pragma unroll
    for (int m = 1; m < 64; m <<= 1) {
        sum += __shfl_xor(sum, m);
        last = max(last, __shfl_xor(last, m));
    }
    __shared__ float ssum[4]; __shared__ int slast[4];
    if ((tid & 63) == 0) { ssum[tid >> 6] = sum; slast[tid >> 6] = last; }
    __syncthreads();
    if (tid == 0) {
        const float t = ssum[0] + ssum[1] + ssum[2] + ssum[3];
        const int ml = max(max(slast[0], slast[1]), max(slast[2], slast[3]));
        imp_mean[b] = t / (float)SS;
        exists[b] = (ml >= 0) ? 1 : 0;
        s_star[b] = (ml >= 0) ? ml : (SS - 1);
    }
}

// rowmean over H of write_weights; one wave per row
__global__ __launch_bounds__(256) void rowmean_kernel(
    const float* __restrict__ ww, float* __restrict__ rm)
{
    const int wv = threadIdx.x >> 6, lane = threadIdx.x & 63;
    const int row = blockIdx.x * 4 + wv;
    const float* p = ww + (size_t)row * HH + lane * 8;
    const float4 v0 = *(const float4*)p;
    const float4 v1 = *(const float4*)(p + 4);
    float s = v0.x + v0.y + v0.z + v0.w + v1.x + v1.y + v1.z + v1.w;
#pragma unroll
    for (int m = 1; m < 64; m <<= 1) s += __shfl_xor(s, m);
    if (lane == 0) rm[row] = s * (1.0f / (float)HH);
}

// per batch: first-occurrence argmax over M rowmeans
__global__ __launch_bounds__(256) void argmax_kernel(
    const float* __restrict__ rm, int* __restrict__ pos)
{
    const int b = blockIdx.x, tid = threadIdx.x;
    float best = -3.0e38f; int bidx = 1 << 30;
    for (int m = tid; m < MM; m += 256) {
        const float v = rm[b * MM + m];
        if (v > best || (v == best && m < bidx)) { best = v; bidx = m; }
    }
#pragma unroll
    for (int msk = 1; msk < 64; msk <<= 1) {
        const float ov = __shfl_xor(best, msk);
        const int oi = __shfl_xor(bidx, msk);
        if (ov > best || (ov == best && oi < bidx)) { best = ov; bidx = oi; }
    }
    __shared__ float sv[4]; __shared__ int si[4];
    if ((tid & 63) == 0) { sv[tid >> 6] = best; si[tid >> 6] = bidx; }
    __syncthreads();
    if (tid == 0) {
        for (int w = 1; w < 4; ++w)
            if (sv[w] > best || (sv[w] == best && si[w] < bidx)) { best = sv[w]; bidx = si[w]; }
        pos[b] = bidx;
    }
}

// per batch: upd = tanh(relu([old,sel]@Wu1+bu1)@Wu2+bu2); write updated row
__global__ __launch_bounds__(256) void update_kernel(
    const float* __restrict__ mb, const float* __restrict__ ni,
    const float* __restrict__ Wu1, const float* __restrict__ bu1,
    const float* __restrict__ Wu2, const float* __restrict__ bu2,
    const float* __restrict__ wwp, const int* __restrict__ pos,
    const int* __restrict__ s_star, const int* __restrict__ exists,
    float* __restrict__ outu)
{
    const int b = blockIdx.x, tid = threadIdx.x;
    __shared__ float comb[2 * DD];
    __shared__ float hu[HH];
    const int p = pos[b], ss = s_star[b], ex = exists[b];
    const float* oldp = mb + ((size_t)(b * MM + p)) * DD;
    const float* selp = ni + ((size_t)(b * SS + ss)) * DD;
    for (int i = tid; i < DD; i += 256) { comb[i] = oldp[i]; comb[DD + i] = selp[i]; }
    __syncthreads();
#pragma unroll
    for (int t = 0; t < 2; ++t) {
        const int n = tid + t * 256;
        float a = bu1[n];
        for (int k = 0; k < 2 * DD; ++k) a = fmaf(comb[k], Wu1[(size_t)k * HH + n], a);
        hu[n] = fmaxf(a, 0.f);
    }
    __syncthreads();
#pragma unroll
    for (int t = 0; t < 2; ++t) {
        const int n = tid + t * 256;
        float a = bu2[n];
        for (int k = 0; k < HH; ++k) a = fmaf(hu[k], Wu2[(size_t)k * HH + n], a);
        const float upd = tanhf(a);
        const float wwv = wwp[((size_t)(b * MM + p)) * HH + n];
        const float ov = oldp[n];
        outu[((size_t)(b * MM + p)) * DD + n] = ex ? fmaf(upd, wwv, ov) : ov;
    }
}

extern "C" void kernel_launch(void* const* d_in, const int* in_sizes, int n_in,
                              void* d_out, int out_size, void* d_ws, size_t ws_size,
                              hipStream_t stream)
{
    const float* new_info    = (const float*)d_in[0];
    const float* memory_bank = (const float*)d_in[1];
    const float* W_in = (const float*)d_in[2];  const float* b_in = (const float*)d_in[3];
    const float* Wq   = (const float*)d_in[4];  const float* bq   = (const float*)d_in[5];
    const float* Wk   = (const float*)d_in[6];  const float* bk   = (const float*)d_in[7];
    const float* Wv   = (const float*)d_in[8];  const float* bv   = (const float*)d_in[9];
    const float* Wo   = (const float*)d_in[10]; const float* bo   = (const float*)d_in[11];
    const float* Wi1  = (const float*)d_in[12]; const float* bi1  = (const float*)d_in[13];
    const float* Wi2  = (const float*)d_in[14]; const float* bi2  = (const float*)d_in[15];
    const float* Wu1  = (const float*)d_in[16]; const float* bu1  = (const float*)d_in[17];
    const float* Wu2  = (const float*)d_in[18]; const float* bu2  = (const float*)d_in[19];

    float* out = (float*)d_out;
    float* out_updated = out;                               // B*M*D
    float* out_ww      = out + (size_t)BB * MM * HH;        // B*M*H
    float* out_imp     = out + 2 * (size_t)BB * MM * HH;    // B*S

    // workspace layout (f32 units), ~92 MB
    float* ws = (float*)d_ws;
    float* info_proj = ws;                                  // 4,194,304
    float* qhb       = info_proj + 4194304;                 // 8,388,608 (hidden1 aliases)
    float* kvreg     = qhb + 8388608;                       // 8,388,608 (bf16 splits)
    float* winq      = kvreg + 8388608;                     // 262,144
    float* wtf       = winq + 262144;                       // 1,310,720 (us pairs)
    float* bq_eff    = wtf + 1310720;                       // 512
    float* bkv       = bq_eff + 512;                        // 1024
    float* rowmeanv  = bkv + 1024;                          // 16,384
    float* imp_mean  = rowmeanv + 16384;                    // 8
    int*   ipos      = (int*)(imp_mean + BB);
    int*   istar     = ipos + BB;
    int*   iexists   = istar + BB;

    float* hidden1 = qhb;  // B*S*256, dead before Q-GEMM writes qhb

    us* Kh  = (us*)kvreg;          // [8192][512]
    us* Kl  = Kh + 4194304;
    us* Vth = Kl + 4194304;        // [8][512][1024]
    us* Vtl = Vth + 4194304;

    us* wtq_h   = (us*)wtf;            us* wtq_l   = wtq_h + 262144;
    us* wtkv_h  = wtq_l + 262144;      us* wtkv_l  = wtkv_h + 524288;   // [1024][512]
    us* wto_h   = wtkv_l + 524288;     us* wto_l   = wto_h + 262144;
    us* wtinq_h = wto_l + 262144;      us* wtinq_l = wtinq_h + 262144;

    const dim3 blk(256);

    hipMemcpyAsync(out_updated, memory_bank,
                   (size_t)BB * MM * DD * sizeof(float),
                   hipMemcpyDeviceToDevice, stream);

    // ---- weight prep: Wq, Wk|Wv (concat rows), Wo transposed+split
    TSB ts;
    ts.src[0] = Wq; ts.dh[0] = wtq_h;           ts.dl[0] = wtq_l;
    ts.src[1] = Wk; ts.dh[1] = wtkv_h;          ts.dl[1] = wtkv_l;
    ts.src[2] = Wv; ts.dh[2] = wtkv_h + 262144; ts.dl[2] = wtkv_l + 262144;
    ts.src[3] = Wo; ts.dh[3] = wto_h;           ts.dl[3] = wto_l;
    transpose_split_batch<<<dim3(16, 16, 4), blk, 0, stream>>>(ts);
    concat_bias<<<dim3(4), blk, 0, stream>>>(bk, bv, bkv);
    bias_fuse<<<dim3(2), blk, 0, stream>>>(b_in, Wq, bq, bq_eff);

    // ---- importance path stays exact f32 (imp sits ~1e-6 from 0.5 threshold)
    gemm128<<<dim3(4, 64), blk, 0, stream>>>(new_info, W_in, b_in, info_proj,
                                             DD, HH, 0, nullptr, 1);
    gemm128<<<dim3(2, 64), blk, 0, stream>>>(info_proj, Wi1, bi1, hidden1,
                                             HH, HH / 2, 1, nullptr, 1);
    imp_kernel<<<dim3((BB * SS) / 4), blk, 0, stream>>>(hidden1, Wi2, bi2, out_imp);
    impstats_kernel<<<dim3(BB), blk, 0, stream>>>(out_imp, imp_mean, istar, iexists);

    // ---- fused Q path: winq = W_in@Wq; Q = memory_bank@winq + bq_eff
    gemm_mfma<<<dim3(4, 4), blk, 0, stream>>>(W_in, wtq_h, wtq_l,
                                              nullptr, winq, 512, 512, nullptr, 1);
    TSB ts2;
    ts2.src[0] = winq; ts2.dh[0] = wtinq_h; ts2.dl[0] = wtinq_l;
    transpose_split_batch<<<dim3(16, 16, 1), blk, 0, stream>>>(ts2);
    gemm_mfma<<<dim3(4, 128), blk, 0, stream>>>(memory_bank, wtinq_h, wtinq_l,
                                                bq_eff, qhb, 512, 512, nullptr, 1);

    // ---- fused K|V GEMM -> pre-split K (row-major) + V (transposed)
    gemm_mfma_kv<<<dim3(8, 64), blk, 0, stream>>>(info_proj, wtkv_h, wtkv_l,
                                                  bkv, Kh, Kl, Vth, Vtl, 512);

    // ---- MFMA flash attention (writes back into qhb; each block owns its rows)
    attn_mfma<<<dim3(2048), blk, 0, stream>>>(qhb, Kh, Kl, Vth, Vtl, qhb);

    // ---- output projection (+ imp_mean rowscale) -> write_weights
    gemm_mfma<<<dim3(4, 128), blk, 0, stream>>>(qhb, wto_h, wto_l,
                                                bo, out_ww, 512, 512, imp_mean, MM);

    // ---- slot selection + final row update
    rowmean_kernel<<<dim3((BB * MM) / 4), blk, 0, stream>>>(out_ww, rowmeanv);
    argmax_kernel<<<dim3(BB), blk, 0, stream>>>(rowmeanv, ipos);
    update_kernel<<<dim3(BB), blk, 0, stream>>>(memory_bank, new_info,
                                                Wu1, bu1, Wu2, bu2, out_ww,
                                                ipos, istar, iexists, out_updated);
}

// Round 9
// 588.878 us; speedup vs baseline: 1.2777x; 1.2777x over previous
//
#include <hip/hip_runtime.h>
#include <math.h>

// Problem constants (AttentionWriter): B=8,S=1024,M=2048,D=512,H=512,NH=8,Dh=64
#define BB 8
#define SS 1024
#define MM 2048
#define DD 512
#define HH 512
#define NHEAD 8
#define DHEAD 64

typedef __attribute__((ext_vector_type(8))) short short8;
typedef __attribute__((ext_vector_type(4))) float f32x4;
typedef unsigned short us;

// bf16 split helpers (RNE)
__device__ __forceinline__ us bf_hi(float x) {
    unsigned u = __float_as_uint(x);
    return (us)((u + 0x7FFFu + ((u >> 16) & 1u)) >> 16);
}
__device__ __forceinline__ float bf_f(us h) {
    return __uint_as_float(((unsigned)h) << 16);
}
__device__ __forceinline__ void split_pack4(float a, float b, float c, float d,
                                            uint2& hp, uint2& lp) {
    us h0 = bf_hi(a), h1 = bf_hi(b), h2 = bf_hi(c), h3 = bf_hi(d);
    hp.x = (unsigned)h0 | ((unsigned)h1 << 16);
    hp.y = (unsigned)h2 | ((unsigned)h3 << 16);
    us l0 = bf_hi(a - bf_f(h0)), l1 = bf_hi(b - bf_f(h1));
    us l2 = bf_hi(c - bf_f(h2)), l3 = bf_hi(d - bf_f(h3));
    lp.x = (unsigned)l0 | ((unsigned)l1 << 16);
    lp.y = (unsigned)l2 | ((unsigned)l3 << 16);
}

// async global->LDS DMA, 16B per lane; LDS dest = wave-uniform base + lane*16
__device__ __forceinline__ void gload_lds16(const void* g, void* l) {
    __builtin_amdgcn_global_load_lds(
        (__attribute__((address_space(1))) void*)(g),
        (__attribute__((address_space(3))) void*)(l), 16, 0, 0);
}

// ---------------------------------------------------------------------------
// f32 GEMM (precision-sensitive importance path ONLY)
// ---------------------------------------------------------------------------
__global__ __launch_bounds__(256) void gemm128(
    const float* __restrict__ A, const float* __restrict__ W,
    const float* __restrict__ bias, float* __restrict__ C,
    int K, int N, int act, const float* __restrict__ rowscale, int rsdiv)
{
    __shared__ float As[8][132];
    __shared__ float Bs[8][128];
    const int tid  = threadIdx.x;
    const int row0 = blockIdx.y * 128, col0 = blockIdx.x * 128;
    const int ty = tid >> 4, tx = tid & 15;

    const int arow = tid >> 1,  ak4  = (tid & 1) * 4;
    const int bk   = tid >> 5,  bcol = (tid & 31) * 4;

    const float* Ap = A + (size_t)(row0 + arow) * K + ak4;
    const float* Wp = W + (size_t)bk * N + col0 + bcol;

    float4 aReg = *(const float4*)Ap;
    float4 bReg = *(const float4*)Wp;

    float acc[8][8];
#pragma unroll
    for (int i = 0; i < 8; ++i)
#pragma unroll
        for (int j = 0; j < 8; ++j) acc[i][j] = 0.f;

    for (int k0 = 0; k0 < K; k0 += 8) {
        __syncthreads();
        As[ak4 + 0][arow] = aReg.x;
        As[ak4 + 1][arow] = aReg.y;
        As[ak4 + 2][arow] = aReg.z;
        As[ak4 + 3][arow] = aReg.w;
        *(float4*)&Bs[bk][bcol] = bReg;
        __syncthreads();
        if (k0 + 8 < K) {
            aReg = *(const float4*)(Ap + k0 + 8);
            bReg = *(const float4*)(Wp + (size_t)(k0 + 8) * N);
        }
#pragma unroll
        for (int kk = 0; kk < 8; ++kk) {
            float a[8], b[8];
            *(float4*)&a[0] = *(const float4*)&As[kk][ty * 8];
            *(float4*)&a[4] = *(const float4*)&As[kk][ty * 8 + 4];
            *(float4*)&b[0] = *(const float4*)&Bs[kk][tx * 4];
            *(float4*)&b[4] = *(const float4*)&Bs[kk][64 + tx * 4];
#pragma unroll
            for (int i = 0; i < 8; ++i)
#pragma unroll
                for (int j = 0; j < 8; ++j)
                    acc[i][j] = fmaf(a[i], b[j], acc[i][j]);
        }
    }

#pragma unroll
    for (int i = 0; i < 8; ++i) {
        const int r = row0 + ty * 8 + i;
        const float sc = rowscale ? rowscale[r / rsdiv] : 1.0f;
#pragma unroll
        for (int half = 0; half < 2; ++half) {
            const int c = col0 + half * 64 + tx * 4;
            float4 bv = bias ? *(const float4*)&bias[c] : make_float4(0.f, 0.f, 0.f, 0.f);
            float4 v;
            v.x = acc[i][half * 4 + 0] + bv.x;
            v.y = acc[i][half * 4 + 1] + bv.y;
            v.z = acc[i][half * 4 + 2] + bv.z;
            v.w = acc[i][half * 4 + 3] + bv.w;
            if (act == 1) {
                v.x = fmaxf(v.x, 0.f); v.y = fmaxf(v.y, 0.f);
                v.z = fmaxf(v.z, 0.f); v.w = fmaxf(v.w, 0.f);
            }
            v.x *= sc; v.y *= sc; v.z *= sc; v.w *= sc;
            *(float4*)&C[(size_t)r * N + c] = v;
        }
    }
}

// ---------------------------------------------------------------------------
// batched transpose+split of [512][512] f32 weights -> [n][k] bf16 hi/lo
// ---------------------------------------------------------------------------
struct TSB {
    const float* src[6];
    us* dh[6];
    us* dl[6];
};
__global__ __launch_bounds__(256) void transpose_split_batch(TSB a)
{
    __shared__ float tile[32][33];
    const int tid = threadIdx.x;
    const int n0 = blockIdx.x * 32, k0 = blockIdx.y * 32;
    const int wsel = blockIdx.z;
    const float* W = a.src[wsel];
    {
        const int r = tid >> 3, c = (tid & 7) * 4;
        const float4 v = *(const float4*)(W + (size_t)(k0 + r) * 512 + n0 + c);
        tile[r][c + 0] = v.x; tile[r][c + 1] = v.y;
        tile[r][c + 2] = v.z; tile[r][c + 3] = v.w;
    }
    __syncthreads();
    {
        const int n = tid >> 3, k = (tid & 7) * 4;
        uint2 hp, lp;
        split_pack4(tile[k + 0][n], tile[k + 1][n], tile[k + 2][n], tile[k + 3][n], hp, lp);
        *(uint2*)(a.dh[wsel] + (size_t)(n0 + n) * 512 + k0 + k) = hp;
        *(uint2*)(a.dl[wsel] + (size_t)(n0 + n) * 512 + k0 + k) = lp;
    }
}

// fused bias for Q: out[n] = b_in @ Wq + bq   (coalesced across n)
__global__ __launch_bounds__(256) void bias_fuse(
    const float* __restrict__ b_in, const float* __restrict__ Wq,
    const float* __restrict__ bq, float* __restrict__ out)
{
    const int n = blockIdx.x * 256 + threadIdx.x;
    float a = bq[n];
    for (int k = 0; k < 512; ++k) a = fmaf(b_in[k], Wq[(size_t)k * 512 + n], a);
    out[n] = a;
}

// concat bk|bv -> bkv[1024]
__global__ __launch_bounds__(256) void concat_bias(
    const float* __restrict__ a, const float* __restrict__ b, float* __restrict__ o)
{
    const int i = blockIdx.x * 256 + threadIdx.x;
    o[i] = (i < 512) ? a[i] : b[i - 512];
}

// ---------------------------------------------------------------------------
// Split-bf16 MFMA GEMM core (3-term), f32 A split in-kernel; B pre-split [N][K].
// Tile 128x128, BK=64, 4 waves (2x2), 4x4 16x16x32 frags/wave. f32 C epilogue.
// ---------------------------------------------------------------------------
#define GEMM_MFMA_BODY(K_)                                                          \
    __shared__ us sm[32768];                                                        \
    us* sAh = sm;            us* sAl = sm + 8192;                                   \
    us* sBh = sm + 16384;    us* sBl = sm + 24576;                                  \
    const int tid = threadIdx.x, lane = tid & 63;                                   \
    const int wid = tid >> 6, wm = wid >> 1, wn = wid & 1;                          \
    const int m0 = blockIdx.y * 128, n0 = blockIdx.x * 128;                         \
    const int fr = lane & 15, fq4 = lane >> 4;                                      \
    f32x4 acc[4][4];                                                                \
    _Pragma("unroll")                                                               \
    for (int i = 0; i < 4; ++i)                                                     \
        _Pragma("unroll")                                                           \
        for (int j = 0; j < 4; ++j)                                                 \
            _Pragma("unroll")                                                       \
            for (int r = 0; r < 4; ++r) acc[i][j][r] = 0.f;                         \
    const int ar = tid >> 4;                                                        \
    const int ak = (tid & 15) * 4;                                                  \
    int bsrow[4], bsf[4], bsoff[4];                                                 \
    _Pragma("unroll")                                                               \
    for (int it = 0; it < 4; ++it) {                                                \
        const int s = tid + 256 * it;                                               \
        bsrow[it] = s >> 3;                                                         \
        bsf[it] = s & 7;                                                            \
        bsoff[it] = bsrow[it] * 64 + ((bsf[it] ^ (bsrow[it] & 7)) << 3);            \
    }                                                                               \
    float4 aR[8];                                                                   \
    uint4 bhR[4], blR[4];                                                           \
    _Pragma("unroll")                                                               \
    for (int p = 0; p < 8; ++p)                                                     \
        aR[p] = *(const float4*)(A + (size_t)(m0 + p * 16 + ar) * (K_) + ak);       \
    _Pragma("unroll")                                                               \
    for (int it = 0; it < 4; ++it) {                                                \
        const size_t bo = (size_t)(n0 + bsrow[it]) * (K_) + bsf[it] * 8;            \
        bhR[it] = *(const uint4*)(Bh + bo);                                         \
        blR[it] = *(const uint4*)(Bl + bo);                                         \
    }                                                                               \
    for (int k0 = 0; k0 < (K_); k0 += 64) {                                         \
        __syncthreads();                                                            \
        _Pragma("unroll")                                                           \
        for (int p = 0; p < 8; ++p) {                                               \
            const int r = p * 16 + ar;                                              \
            const int aoff = r * 128 + (((ak >> 3) ^ (r & 7)) << 4) + ((tid & 1) << 3); \
            uint2 hp, lp;                                                           \
            split_pack4(aR[p].x, aR[p].y, aR[p].z, aR[p].w, hp, lp);                \
            *(uint2*)((char*)sAh + aoff) = hp;                                      \
            *(uint2*)((char*)sAl + aoff) = lp;                                      \
        }                                                                           \
        _Pragma("unroll")                                                           \
        for (int it = 0; it < 4; ++it) {                                            \
            *(uint4*)(sBh + bsoff[it]) = bhR[it];                                   \
            *(uint4*)(sBl + bsoff[it]) = blR[it];                                   \
        }                                                                           \
        __syncthreads();                                                            \
        if (k0 + 64 < (K_)) {                                                       \
            _Pragma("unroll")                                                       \
            for (int p = 0; p < 8; ++p)                                             \
                aR[p] = *(const float4*)(A + (size_t)(m0 + p * 16 + ar) * (K_) + k0 + 64 + ak); \
            _Pragma("unroll")                                                       \
            for (int it = 0; it < 4; ++it) {                                        \
                const size_t bo = (size_t)(n0 + bsrow[it]) * (K_) + k0 + 64 + bsf[it] * 8; \
                bhR[it] = *(const uint4*)(Bh + bo);                                 \
                blR[it] = *(const uint4*)(Bl + bo);                                 \
            }                                                                       \
        }                                                                           \
        _Pragma("unroll")                                                           \
        for (int ks = 0; ks < 2; ++ks) {                                            \
            short8 afh[4], afl[4], bfh[4], bfl[4];                                  \
            _Pragma("unroll")                                                       \
            for (int i = 0; i < 4; ++i) {                                           \
                const int row = wm * 64 + i * 16 + fr;                              \
                const int off = row * 128 + (((ks * 4 + fq4) ^ (row & 7)) << 4);    \
                afh[i] = *(const short8*)((const char*)sAh + off);                  \
                afl[i] = *(const short8*)((const char*)sAl + off);                  \
            }                                                                       \
            _Pragma("unroll")                                                       \
            for (int j = 0; j < 4; ++j) {                                           \
                const int row = wn * 64 + j * 16 + fr;                              \
                const int off = row * 128 + (((ks * 4 + fq4) ^ (row & 7)) << 4);    \
                bfh[j] = *(const short8*)((const char*)sBh + off);                  \
                bfl[j] = *(const short8*)((const char*)sBl + off);                  \
            }                                                                       \
            _Pragma("unroll")                                                       \
            for (int i = 0; i < 4; ++i)                                             \
                _Pragma("unroll")                                                   \
                for (int j = 0; j < 4; ++j) {                                       \
                    acc[i][j] = __builtin_amdgcn_mfma_f32_16x16x32_bf16(afh[i], bfh[j], acc[i][j], 0, 0, 0); \
                    acc[i][j] = __builtin_amdgcn_mfma_f32_16x16x32_bf16(afh[i], bfl[j], acc[i][j], 0, 0, 0); \
                    acc[i][j] = __builtin_amdgcn_mfma_f32_16x16x32_bf16(afl[i], bfh[j], acc[i][j], 0, 0, 0); \
                }                                                                   \
        }                                                                           \
    }

__global__ __launch_bounds__(256) void gemm_mfma(
    const float* __restrict__ A,
    const us* __restrict__ Bh, const us* __restrict__ Bl,
    const float* __restrict__ bias, float* __restrict__ C,
    int K, int N, const float* __restrict__ rowscale, int rsdiv)
{
    GEMM_MFMA_BODY(K)
#pragma unroll
    for (int j = 0; j < 4; ++j) {
        const int col = n0 + wn * 64 + j * 16 + fr;
        const float bj = bias ? bias[col] : 0.f;
#pragma unroll
        for (int i = 0; i < 4; ++i) {
#pragma unroll
            for (int r = 0; r < 4; ++r) {
                const int row = m0 + wm * 64 + i * 16 + fq4 * 4 + r;
                float v = acc[i][j][r] + bj;
                if (rowscale) v *= rowscale[row / rsdiv];
                C[(size_t)row * N + col] = v;
            }
        }
    }
}

// KV GEMM: N=1024 (Wk|Wv). cols<512 -> K rows [B*S][512] bf16 hi/lo;
// cols>=512 -> V TRANSPOSED [B][512 d][1024 s] bf16 hi/lo.
__global__ __launch_bounds__(256) void gemm_mfma_kv(
    const float* __restrict__ A,
    const us* __restrict__ Bh, const us* __restrict__ Bl,
    const float* __restrict__ bias,
    us* __restrict__ Kh, us* __restrict__ Kl,
    us* __restrict__ Vth, us* __restrict__ Vtl, int K)
{
    GEMM_MFMA_BODY(K)
    if (n0 < 512) {
#pragma unroll
        for (int j = 0; j < 4; ++j) {
            const int col = n0 + wn * 64 + j * 16 + fr;
            const float bj = bias[col];
#pragma unroll
            for (int i = 0; i < 4; ++i)
#pragma unroll
                for (int r = 0; r < 4; ++r) {
                    const int row = m0 + wm * 64 + i * 16 + fq4 * 4 + r;
                    const float v = acc[i][j][r] + bj;
                    const us hv = bf_hi(v);
                    Kh[(size_t)row * 512 + col] = hv;
                    Kl[(size_t)row * 512 + col] = bf_hi(v - bf_f(hv));
                }
        }
    } else {
#pragma unroll
        for (int j = 0; j < 4; ++j) {
            const int col = n0 + wn * 64 + j * 16 + fr;
            const float bj = bias[col];
            const int d = col - 512;
#pragma unroll
            for (int i = 0; i < 4; ++i) {
                const int row0 = m0 + wm * 64 + i * 16 + fq4 * 4;
                uint2 hp, lp;
                split_pack4(acc[i][j][0] + bj, acc[i][j][1] + bj,
                            acc[i][j][2] + bj, acc[i][j][3] + bj, hp, lp);
                const size_t vo = ((size_t)(row0 >> 10) * 512 + d) * 1024 + (row0 & 1023);
                *(uint2*)(Vth + vo) = hp;
                *(uint2*)(Vtl + vo) = lp;
            }
        }
    }
}

// ---------------------------------------------------------------------------
// MFMA flash attention v4: 64 q-rows/block, 4 waves, LDS 48.25KB (3 blocks/CU).
// K/V staged via global_load_lds (direct DMA, no VGPR round-trip): R6-R8's
// register prefetch block (8x uint4) was spilled to scratch (~770MB/dispatch)
// by the allocator targeting 8 waves/EU; attributes couldn't stop it, so the
// staging state is removed structurally. LDS stays linear per-lane; the XOR
// frag swizzle is applied by pre-swizzling the per-lane GLOBAL source addr
// (legal: each row slice is a contiguous 128B; swizzle permutes 16B frags
// within the row). Wave w stages array w (Kh|Kl|Vh|Vl), 8x 1KB issues;
// __syncthreads() drains vmcnt -> staged data visible.
// ---------------------------------------------------------------------------
__global__ __launch_bounds__(256) void attn_mfma(
    const float* __restrict__ qh,
    const us* __restrict__ Kh, const us* __restrict__ Kl,
    const us* __restrict__ Vth, const us* __restrict__ Vtl,
    float* __restrict__ outp)
{
    __shared__ us sm[24576];    // sKh|sKl|sVh|sVl (4096 us each) | sPh|sPl
    __shared__ float sSc[64];
    us* sKh = sm;            us* sKl = sm + 4096;
    us* sVh = sm + 8192;     us* sVl = sm + 12288;
    us* sPh = sm + 16384;    us* sPl = sm + 20480;

    const int tid = threadIdx.x, lane = tid & 63, w = tid >> 6;
    const int fr = lane & 15, fq4 = lane >> 4;

    // XCD swizzle: 32 blocks sharing one (b,h) K/V slice land on one XCD
    const int wg = blockIdx.x;              // 0..2047
    const int xcd = wg & 7, ix = wg >> 3;   // ix 0..255
    const int mt = ix & 31;
    const int pair = xcd + 8 * (ix >> 5);   // 0..63
    const int h = pair & 7, b = pair >> 3;
    const int m0 = mt * 64;

    const float* Qg = qh + ((size_t)(b * MM + m0)) * HH + h * DHEAD;
    const us* Kgh = Kh + ((size_t)b * SS) * 512 + h * DHEAD;
    const us* Kgl = Kl + ((size_t)b * SS) * 512 + h * DHEAD;
    const us* Vgh = Vth + ((size_t)b * 512 + h * DHEAD) * 1024;
    const us* Vgl = Vtl + ((size_t)b * 512 + h * DHEAD) * 1024;
    float* Og = outp + ((size_t)(b * MM + m0)) * HH + h * DHEAD;

    // ---- Q fragments in registers (pre-scaled by 1/8), hi/lo split
    short8 qfh[2], qfl[2];   // [ks]
#pragma unroll
    for (int ks = 0; ks < 2; ++ks) {
        const float* qp = Qg + (size_t)(w * 16 + fr) * HH + ks * 32 + fq4 * 8;
        const float4 u0 = *(const float4*)qp;
        const float4 u1 = *(const float4*)(qp + 4);
        float v[8] = {u0.x, u0.y, u0.z, u0.w, u1.x, u1.y, u1.z, u1.w};
#pragma unroll
        for (int e = 0; e < 8; ++e) {
            const float x = v[e] * 0.125f;
            const us hb = bf_hi(x);
            qfh[ks][e] = (short)hb;
            qfl[ks][e] = (short)bf_hi(x - bf_f(hb));
        }
    }

    // DMA staging assignment: wave w stages array w; per issue i (0..7) it
    // covers rows i*8..i*8+7 (1KB). lane -> (row = i*8 + lane>>3, fp = lane&7);
    // LDS slot (row, fp) must hold global frag fp ^ (row&7).
    const int fp = lane & 7;
    const int rsub = lane >> 3;
    const bool isK = (w < 2);
    const us* gA = (w == 0) ? Kgh : (w == 1) ? Kgl : (w == 2) ? Vgh : Vgl;
    us* lbase = sm + w * 4096;

    f32x4 oacc[4];
#pragma unroll
    for (int j = 0; j < 4; ++j)
#pragma unroll
        for (int r = 0; r < 4; ++r) oacc[j][r] = 0.f;
    float mrun = -1e30f, lrun = 0.f;

    for (int t = 0; t < SS / 64; ++t) {
        __syncthreads();                 // prev chunk's LDS reads done
        if (isK) {
#pragma unroll
            for (int i = 0; i < 8; ++i) {
                const int row = i * 8 + rsub;
                const us* g = gA + (size_t)(t * 64 + row) * 512 + ((fp ^ (row & 7)) << 3);
                gload_lds16(g, lbase + i * 512);
            }
        } else {
#pragma unroll
            for (int i = 0; i < 8; ++i) {
                const int row = i * 8 + rsub;   // row = d
                const us* g = gA + (size_t)row * 1024 + t * 64 + ((fp ^ (row & 7)) << 3);
                gload_lds16(g, lbase + i * 512);
            }
        }
        __syncthreads();                 // drains vmcnt -> staging visible

        // ---- QK^T (swapped): stt[fs] = K-slice x Q^T; C: row=s, col=q=fr
        f32x4 stt[4];
#pragma unroll
        for (int fs = 0; fs < 4; ++fs)
#pragma unroll
            for (int r = 0; r < 4; ++r) stt[fs][r] = 0.f;
#pragma unroll
        for (int ks = 0; ks < 2; ++ks) {
            short8 kfh[4], kfl[4];
#pragma unroll
            for (int fs = 0; fs < 4; ++fs) {
                const int row = fs * 16 + fr;
                const int off = row * 128 + (((ks * 4 + fq4) ^ (row & 7)) << 4);
                kfh[fs] = *(const short8*)((const char*)sKh + off);
                kfl[fs] = *(const short8*)((const char*)sKl + off);
            }
#pragma unroll
            for (int fs = 0; fs < 4; ++fs) {
                stt[fs] = __builtin_amdgcn_mfma_f32_16x16x32_bf16(kfh[fs], qfh[ks], stt[fs], 0, 0, 0);
                stt[fs] = __builtin_amdgcn_mfma_f32_16x16x32_bf16(kfh[fs], qfl[ks], stt[fs], 0, 0, 0);
                stt[fs] = __builtin_amdgcn_mfma_f32_16x16x32_bf16(kfl[fs], qfh[ks], stt[fs], 0, 0, 0);
            }
        }

        // ---- online softmax (q = fr; s spans 4 regs x 4 fs x 4 quarters)
        {
            float mx = stt[0][0];
#pragma unroll
            for (int fs = 0; fs < 4; ++fs)
#pragma unroll
                for (int r = 0; r < 4; ++r) mx = fmaxf(mx, stt[fs][r]);
            mx = fmaxf(mx, __shfl_xor(mx, 16));
            mx = fmaxf(mx, __shfl_xor(mx, 32));
            const float nm = fmaxf(mrun, mx);
            const float scf = __expf(mrun - nm);
            mrun = nm;
            float ps = 0.f;
#pragma unroll
            for (int fs = 0; fs < 4; ++fs)
#pragma unroll
                for (int r = 0; r < 4; ++r) {
                    const float p = __expf(stt[fs][r] - nm);
                    stt[fs][r] = p;
                    ps += p;
                }
            ps += __shfl_xor(ps, 16);
            ps += __shfl_xor(ps, 32);
            lrun = lrun * scf + ps;
            if (fq4 == 0) sSc[w * 16 + fr] = scf;
        }

        // ---- write P[q][s] hi/lo (wave-private rows, no barrier needed)
#pragma unroll
        for (int fs = 0; fs < 4; ++fs) {
            const int q = w * 16 + fr;
            const int flog = (fs << 1) | (fq4 >> 1);
            const int off = q * 128 + ((flog ^ (q & 7)) << 4) + ((fq4 & 1) << 3);
            uint2 hp, lp;
            split_pack4(stt[fs][0], stt[fs][1], stt[fs][2], stt[fs][3], hp, lp);
            *(uint2*)((char*)sPh + off) = hp;
            *(uint2*)((char*)sPl + off) = lp;
        }

        // ---- rescale oacc (q = w*16 + fq4*4 + r)
#pragma unroll
        for (int r = 0; r < 4; ++r) {
            const float scv = sSc[w * 16 + fq4 * 4 + r];
#pragma unroll
            for (int fd = 0; fd < 4; ++fd) oacc[fd][r] *= scv;
        }

        // ---- PV: oacc[fd] += P x V
#pragma unroll
        for (int ks = 0; ks < 2; ++ks) {
            short8 pfh, pfl, vfh[4], vfl[4];
            {
                const int row = w * 16 + fr;
                const int off = row * 128 + (((ks * 4 + fq4) ^ (row & 7)) << 4);
                pfh = *(const short8*)((const char*)sPh + off);
                pfl = *(const short8*)((const char*)sPl + off);
            }
#pragma unroll
            for (int fd = 0; fd < 4; ++fd) {
                const int row = fd * 16 + fr;
                const int off = row * 128 + (((ks * 4 + fq4) ^ (row & 7)) << 4);
                vfh[fd] = *(const short8*)((const char*)sVh + off);
                vfl[fd] = *(const short8*)((const char*)sVl + off);
            }
#pragma unroll
            for (int fd = 0; fd < 4; ++fd) {
                oacc[fd] = __builtin_amdgcn_mfma_f32_16x16x32_bf16(pfh, vfh[fd], oacc[fd], 0, 0, 0);
                oacc[fd] = __builtin_amdgcn_mfma_f32_16x16x32_bf16(pfh, vfl[fd], oacc[fd], 0, 0, 0);
                oacc[fd] = __builtin_amdgcn_mfma_f32_16x16x32_bf16(pfl, vfh[fd], oacc[fd], 0, 0, 0);
            }
        }
    }

    // ---- normalize + store
    if (fq4 == 0) sSc[w * 16 + fr] = lrun;
#pragma unroll
    for (int r = 0; r < 4; ++r) {
        const float inv = 1.0f / sSc[w * 16 + fq4 * 4 + r];
        const int q = w * 16 + fq4 * 4 + r;
#pragma unroll
        for (int fd = 0; fd < 4; ++fd)
            Og[(size_t)q * HH + fd * 16 + fr] = oacc[fd][r] * inv;
    }
}

// imp[row] = sigmoid(dot(h1[row,0:256], Wi2) + bi2); one wave per row
__global__ __launch_bounds__(256) void imp_kernel(
    const float* __restrict__ h1, const float* __restrict__ Wi2,
    const float* __restrict__ bi2, float* __restrict__ imp)
{
    const int wv = threadIdx.x >> 6, lane = threadIdx.x & 63;
    const int row = blockIdx.x * 4 + wv;
    const float4 hv = *(const float4*)(h1 + (size_t)row * 256 + lane * 4);
    const float4 wvv = *(const float4*)(Wi2 + lane * 4);
    float s = hv.x * wvv.x + hv.y * wvv.y + hv.z * wvv.z + hv.w * wvv.w;
#pragma unroll
    for (int m = 1; m < 64; m <<= 1) s += __shfl_xor(s, m);
    if (lane == 0) imp[row] = 1.0f / (1.0f + expf(-(s + bi2[0])));
}

// per batch: mean(imp), last index with imp>0.5, exists
__global__ __launch_bounds__(256) void impstats_kernel(
    const float* __restrict__ imp, float* __restrict__ imp_mean,
    int* __restrict__ s_star, int* __restrict__ exists)
{
    const int b = blockIdx.x, tid = threadIdx.x;
    float sum = 0.f; int last = -1;
    for (int s = tid; s < SS; s += 256) {
        const float v = imp[b * SS + s];
        sum += v;
        if (v > 0.5f) last = s;
    }
#pragma unroll
    for (int m = 1; m < 64; m <<= 1) {
        sum += __shfl_xor(sum, m);
        last = max(last, __shfl_xor(last, m));
    }
    __shared__ float ssum[4]; __shared__ int slast[4];
    if ((tid & 63) == 0) { ssum[tid >> 6] = sum; slast[tid >> 6] = last; }
    __syncthreads();
    if (tid == 0) {
        const float t = ssum[0] + ssum[1] + ssum[2] + ssum[3];
        const int ml = max(max(slast[0], slast[1]), max(slast[2], slast[3]));
        imp_mean[b] = t / (float)SS;
        exists[b] = (ml >= 0) ? 1 : 0;
        s_star[b] = (ml >= 0) ? ml : (SS - 1);
    }
}

// rowmean over H of write_weights; one wave per row
__global__ __launch_bounds__(256) void rowmean_kernel(
    const float* __restrict__ ww, float* __restrict__ rm)
{
    const int wv = threadIdx.x >> 6, lane = threadIdx.x & 63;
    const int row = blockIdx.x * 4 + wv;
    const float* p = ww + (size_t)row * HH + lane * 8;
    const float4 v0 = *(const float4*)p;
    const float4 v1 = *(const float4*)(p + 4);
    float s = v0.x + v0.y + v0.z + v0.w + v1.x + v1.y + v1.z + v1.w;
#pragma unroll
    for (int m = 1; m < 64; m <<= 1) s += __shfl_xor(s, m);
    if (lane == 0) rm[row] = s * (1.0f / (float)HH);
}

// per batch: first-occurrence argmax over M rowmeans
__global__ __launch_bounds__(256) void argmax_kernel(
    const float* __restrict__ rm, int* __restrict__ pos)
{
    const int b = blockIdx.x, tid = threadIdx.x;
    float best = -3.0e38f; int bidx = 1 << 30;
    for (int m = tid; m < MM; m += 256) {
        const float v = rm[b * MM + m];
        if (v > best || (v == best && m < bidx)) { best = v; bidx = m; }
    }
#pragma unroll
    for (int msk = 1; msk < 64; msk <<= 1) {
        const float ov = __shfl_xor(best, msk);
        const int oi = __shfl_xor(bidx, msk);
        if (ov > best || (ov == best && oi < bidx)) { best = ov; bidx = oi; }
    }
    __shared__ float sv[4]; __shared__ int si[4];
    if ((tid & 63) == 0) { sv[tid >> 6] = best; si[tid >> 6] = bidx; }
    __syncthreads();
    if (tid == 0) {
        for (int w = 1; w < 4; ++w)
            if (sv[w] > best || (sv[w] == best && si[w] < bidx)) { best = sv[w]; bidx = si[w]; }
        pos[b] = bidx;
    }
}

// per batch: upd = tanh(relu([old,sel]@Wu1+bu1)@Wu2+bu2); write updated row
__global__ __launch_bounds__(256) void update_kernel(
    const float* __restrict__ mb, const float* __restrict__ ni,
    const float* __restrict__ Wu1, const float* __restrict__ bu1,
    const float* __restrict__ Wu2, const float* __restrict__ bu2,
    const float* __restrict__ wwp, const int* __restrict__ pos,
    const int* __restrict__ s_star, const int* __restrict__ exists,
    float* __restrict__ outu)
{
    const int b = blockIdx.x, tid = threadIdx.x;
    __shared__ float comb[2 * DD];
    __shared__ float hu[HH];
    const int p = pos[b], ss = s_star[b], ex = exists[b];
    const float* oldp = mb + ((size_t)(b * MM + p)) * DD;
    const float* selp = ni + ((size_t)(b * SS + ss)) * DD;
    for (int i = tid; i < DD; i += 256) { comb[i] = oldp[i]; comb[DD + i] = selp[i]; }
    __syncthreads();
#pragma unroll
    for (int t = 0; t < 2; ++t) {
        const int n = tid + t * 256;
        float a = bu1[n];
        for (int k = 0; k < 2 * DD; ++k) a = fmaf(comb[k], Wu1[(size_t)k * HH + n], a);
        hu[n] = fmaxf(a, 0.f);
    }
    __syncthreads();
#pragma unroll
    for (int t = 0; t < 2; ++t) {
        const int n = tid + t * 256;
        float a = bu2[n];
        for (int k = 0; k < HH; ++k) a = fmaf(hu[k], Wu2[(size_t)k * HH + n], a);
        const float upd = tanhf(a);
        const float wwv = wwp[((size_t)(b * MM + p)) * HH + n];
        const float ov = oldp[n];
        outu[((size_t)(b * MM + p)) * DD + n] = ex ? fmaf(upd, wwv, ov) : ov;
    }
}

extern "C" void kernel_launch(void* const* d_in, const int* in_sizes, int n_in,
                              void* d_out, int out_size, void* d_ws, size_t ws_size,
                              hipStream_t stream)
{
    const float* new_info    = (const float*)d_in[0];
    const float* memory_bank = (const float*)d_in[1];
    const float* W_in = (const float*)d_in[2];  const float* b_in = (const float*)d_in[3];
    const float* Wq   = (const float*)d_in[4];  const float* bq   = (const float*)d_in[5];
    const float* Wk   = (const float*)d_in[6];  const float* bk   = (const float*)d_in[7];
    const float* Wv   = (const float*)d_in[8];  const float* bv   = (const float*)d_in[9];
    const float* Wo   = (const float*)d_in[10]; const float* bo   = (const float*)d_in[11];
    const float* Wi1  = (const float*)d_in[12]; const float* bi1  = (const float*)d_in[13];
    const float* Wi2  = (const float*)d_in[14]; const float* bi2  = (const float*)d_in[15];
    const float* Wu1  = (const float*)d_in[16]; const float* bu1  = (const float*)d_in[17];
    const float* Wu2  = (const float*)d_in[18]; const float* bu2  = (const float*)d_in[19];

    float* out = (float*)d_out;
    float* out_updated = out;                               // B*M*D
    float* out_ww      = out + (size_t)BB * MM * HH;        // B*M*H
    float* out_imp     = out + 2 * (size_t)BB * MM * HH;    // B*S

    // workspace layout (f32 units), ~92 MB
    float* ws = (float*)d_ws;
    float* info_proj = ws;                                  // 4,194,304
    float* qhb       = info_proj + 4194304;                 // 8,388,608 (hidden1 aliases)
    float* kvreg     = qhb + 8388608;                       // 8,388,608 (bf16 splits)
    float* winq      = kvreg + 8388608;                     // 262,144
    float* wtf       = winq + 262144;                       // 1,310,720 (us pairs)
    float* bq_eff    = wtf + 1310720;                       // 512
    float* bkv       = bq_eff + 512;                        // 1024
    float* rowmeanv  = bkv + 1024;                          // 16,384
    float* imp_mean  = rowmeanv + 16384;                    // 8
    int*   ipos      = (int*)(imp_mean + BB);
    int*   istar     = ipos + BB;
    int*   iexists   = istar + BB;

    float* hidden1 = qhb;  // B*S*256, dead before Q-GEMM writes qhb

    us* Kh  = (us*)kvreg;          // [8192][512]
    us* Kl  = Kh + 4194304;
    us* Vth = Kl + 4194304;        // [8][512][1024]
    us* Vtl = Vth + 4194304;

    us* wtq_h   = (us*)wtf;            us* wtq_l   = wtq_h + 262144;
    us* wtkv_h  = wtq_l + 262144;      us* wtkv_l  = wtkv_h + 524288;   // [1024][512]
    us* wto_h   = wtkv_l + 524288;     us* wto_l   = wto_h + 262144;
    us* wtinq_h = wto_l + 262144;      us* wtinq_l = wtinq_h + 262144;

    const dim3 blk(256);

    hipMemcpyAsync(out_updated, memory_bank,
                   (size_t)BB * MM * DD * sizeof(float),
                   hipMemcpyDeviceToDevice, stream);

    // ---- weight prep: Wq, Wk|Wv (concat rows), Wo transposed+split
    TSB ts;
    ts.src[0] = Wq; ts.dh[0] = wtq_h;           ts.dl[0] = wtq_l;
    ts.src[1] = Wk; ts.dh[1] = wtkv_h;          ts.dl[1] = wtkv_l;
    ts.src[2] = Wv; ts.dh[2] = wtkv_h + 262144; ts.dl[2] = wtkv_l + 262144;
    ts.src[3] = Wo; ts.dh[3] = wto_h;           ts.dl[3] = wto_l;
    transpose_split_batch<<<dim3(16, 16, 4), blk, 0, stream>>>(ts);
    concat_bias<<<dim3(4), blk, 0, stream>>>(bk, bv, bkv);
    bias_fuse<<<dim3(2), blk, 0, stream>>>(b_in, Wq, bq, bq_eff);

    // ---- importance path stays exact f32 (imp sits ~1e-6 from 0.5 threshold)
    gemm128<<<dim3(4, 64), blk, 0, stream>>>(new_info, W_in, b_in, info_proj,
                                             DD, HH, 0, nullptr, 1);
    gemm128<<<dim3(2, 64), blk, 0, stream>>>(info_proj, Wi1, bi1, hidden1,
                                             HH, HH / 2, 1, nullptr, 1);
    imp_kernel<<<dim3((BB * SS) / 4), blk, 0, stream>>>(hidden1, Wi2, bi2, out_imp);
    impstats_kernel<<<dim3(BB), blk, 0, stream>>>(out_imp, imp_mean, istar, iexists);

    // ---- fused Q path: winq = W_in@Wq; Q = memory_bank@winq + bq_eff
    gemm_mfma<<<dim3(4, 4), blk, 0, stream>>>(W_in, wtq_h, wtq_l,
                                              nullptr, winq, 512, 512, nullptr, 1);
    TSB ts2;
    ts2.src[0] = winq; ts2.dh[0] = wtinq_h; ts2.dl[0] = wtinq_l;
    transpose_split_batch<<<dim3(16, 16, 1), blk, 0, stream>>>(ts2);
    gemm_mfma<<<dim3(4, 128), blk, 0, stream>>>(memory_bank, wtinq_h, wtinq_l,
                                                bq_eff, qhb, 512, 512, nullptr, 1);

    // ---- fused K|V GEMM -> pre-split K (row-major) + V (transposed)
    gemm_mfma_kv<<<dim3(8, 64), blk, 0, stream>>>(info_proj, wtkv_h, wtkv_l,
                                                  bkv, Kh, Kl, Vth, Vtl, 512);

    // ---- MFMA flash attention (writes back into qhb; each block owns its rows)
    attn_mfma<<<dim3(2048), blk, 0, stream>>>(qhb, Kh, Kl, Vth, Vtl, qhb);

    // ---- output projection (+ imp_mean rowscale) -> write_weights
    gemm_mfma<<<dim3(4, 128), blk, 0, stream>>>(qhb, wto_h, wto_l,
                                                bo, out_ww, 512, 512, imp_mean, MM);

    // ---- slot selection + final row update
    rowmean_kernel<<<dim3((BB * MM) / 4), blk, 0, stream>>>(out_ww, rowmeanv);
    argmax_kernel<<<dim3(BB), blk, 0, stream>>>(rowmeanv, ipos);
    update_kernel<<<dim3(BB), blk, 0, stream>>>(memory_bank, new_info,
                                                Wu1, bu1, Wu2, bu2, out_ww,
                                                ipos, istar, iexists, out_updated);
}